// Round 1
// baseline (44773.499 us; speedup 1.0000x reference)
//
#include <hip/hip_runtime.h>
#include <hip/hip_bf16.h>

#define Bb 256
#define Tt 512
#define Ff 256
#define Hh 1024
#define Cc 128
#define NBLK 256
#define NTHR 512

typedef __bf16 bf16;
typedef bf16 bf16x8 __attribute__((ext_vector_type(8)));
typedef float f32x4 __attribute__((ext_vector_type(4)));

#define MFMA(a, b, c) __builtin_amdgcn_mfma_f32_16x16x32_bf16(a, b, c, 0, 0, 0)

struct SMem {
    bf16x8 w[2 * 64 * 64];      // frag-major [(mt*KI+ki)*64+lane]; L2 uses all 128 KB, L1 first 80 KB
    float scratch[32 * 129];    // gate scratch, padded stride 129
    float bias[32];
    bf16 hstage[8 * 256];       // [hu][b] staging for coalesced h writeback
};

__device__ __forceinline__ float fsig(float x) {
    x = fminf(30.f, fmaxf(-30.f, x));
    return __builtin_amdgcn_rcpf(1.f + __expf(-x));
}
__device__ __forceinline__ float ftanh(float x) {
    x = fminf(15.f, fmaxf(-15.f, x));
    float e = __expf(2.f * x);
    return (e - 1.f) * __builtin_amdgcn_rcpf(e + 1.f);
}

__device__ __forceinline__ void grid_barrier(unsigned* cnt, unsigned target) {
    __builtin_amdgcn_fence(__ATOMIC_RELEASE, "agent");  // flush stores device-visible (vmcnt + L2 wb)
    __syncthreads();
    if (threadIdx.x == 0) {
        __hip_atomic_fetch_add(cnt, 1u, __ATOMIC_RELAXED, __HIP_MEMORY_SCOPE_AGENT);
        while (__hip_atomic_load(cnt, __ATOMIC_RELAXED, __HIP_MEMORY_SCOPE_AGENT) < target)
            __builtin_amdgcn_s_sleep(2);
        __builtin_amdgcn_fence(__ATOMIC_ACQUIRE, "agent");  // invalidate L1/L2 so fresh h is visible
    }
    __syncthreads();
}

__device__ __forceinline__ void epilogue(SMem& sm, f32x4 acc00, f32x4 acc01, f32x4 acc10, f32x4 acc11,
                                         float creg[4], bf16* hdst, int hu0, bool extra_tanh) {
    const int tid = threadIdx.x;
    const int lane = tid & 63, wv = tid >> 6, quad = lane >> 4, l15 = lane & 15;
    const int colb = (wv & 3) * 32;
    #pragma unroll
    for (int ph = 0; ph < 2; ++ph) {
        if ((wv >> 2) == ph) {
            #pragma unroll
            for (int r = 0; r < 4; ++r) {
                sm.scratch[(quad * 4 + r) * 129 + colb + l15]           = acc00[r];
                sm.scratch[(quad * 4 + r) * 129 + colb + 16 + l15]      = acc01[r];
                sm.scratch[(16 + quad * 4 + r) * 129 + colb + l15]      = acc10[r];
                sm.scratch[(16 + quad * 4 + r) * 129 + colb + 16 + l15] = acc11[r];
            }
        }
        __syncthreads();
        #pragma unroll
        for (int pi = 0; pi < 2; ++pi) {
            int idx = pi * NTHR + tid;      // 0..1023
            int bl = idx & 127, hu = idx >> 7;
            float gi = sm.scratch[hu * 129 + bl]        + sm.bias[hu];
            float gf = sm.scratch[(8 + hu) * 129 + bl]  + sm.bias[8 + hu];
            float gg = sm.scratch[(16 + hu) * 129 + bl] + sm.bias[16 + hu];
            float go = sm.scratch[(24 + hu) * 129 + bl] + sm.bias[24 + hu];
            float iv = fsig(gi), fv = fsig(gf), gv = ftanh(gg), ov = fsig(go);
            float c = fv * creg[ph * 2 + pi] + iv * gv;
            creg[ph * 2 + pi] = c;
            float h = ov * ftanh(c);
            if (extra_tanh) h = ftanh(h);   // layer-2 stores tanh'd h as recurrent state
            int b = bl + 128 * ph;
            sm.hstage[hu * 256 + b] = (bf16)h;
        }
        __syncthreads();
    }
    if (tid < 256) {
        bf16x8 v;
        #pragma unroll
        for (int e = 0; e < 8; ++e) v[e] = sm.hstage[e * 256 + tid];
        *(bf16x8*)(hdst + (size_t)tid * Hh + hu0) = v;
    }
}

__global__ void __launch_bounds__(NTHR, 2)
lstm_kernel(const float* __restrict__ y,
            const float* __restrict__ Wih1, const float* __restrict__ Whh1,
            const float* __restrict__ bih1, const float* __restrict__ bhh1,
            const float* __restrict__ Wih2, const float* __restrict__ Whh2,
            const float* __restrict__ bih2, const float* __restrict__ bhh2,
            const float* __restrict__ Wout, const float* __restrict__ bout,
            float* __restrict__ out,
            bf16* __restrict__ h1b0, bf16* __restrict__ h1b1,
            bf16* __restrict__ h2b0, bf16* __restrict__ h2b1,
            unsigned* __restrict__ cnt)
{
    __shared__ SMem sm;
    const int tid = threadIdx.x;
    const int bid = blockIdx.x;
    const bool isL2 = bid >= 128;
    const int hu0 = (bid & 127) * 8;
    const int KI = isL2 ? 64 : 40;      // k-iterations: L1 K=1280 (8 x-iters + 32 h), L2 K=2048
    const int lane = tid & 63;
    const int wv = tid >> 6;
    const int quad = lane >> 4;
    const int l15 = lane & 15;

    // ---- one-time init: bias + pack weights into LDS in MFMA A-frag order ----
    if (tid < 32) {
        int gate = tid >> 3, j = tid & 7;
        int grow = gate * Hh + hu0 + j;
        sm.bias[tid] = isL2 ? (bih2[grow] + bhh2[grow]) : (bih1[grow] + bhh1[grow]);
    }
    for (int slot = tid; slot < 2 * KI * 64; slot += NTHR) {
        int mt = slot / (KI * 64);
        int ki = (slot / 64) % KI;
        int ln = slot & 63;
        int row = mt * 16 + (ln & 15);
        int k = ki * 32 + (ln >> 4) * 8;
        int gate = row >> 3, j = row & 7;
        int grow = gate * Hh + hu0 + j;
        const float* src;
        if (!isL2) src = (k < Ff) ? (Wih1 + (size_t)grow * Ff + k) : (Whh1 + (size_t)grow * Hh + (k - Ff));
        else       src = (k < Hh) ? (Wih2 + (size_t)grow * Hh + k) : (Whh2 + (size_t)grow * Hh + (k - Hh));
        bf16x8 fr;
        #pragma unroll
        for (int e = 0; e < 8; ++e) fr[e] = (bf16)src[e];
        sm.w[slot] = fr;
    }
    float creg[4] = {0.f, 0.f, 0.f, 0.f};
    __syncthreads();

    const int nb0 = wv * 32 + l15;      // batch col for nt=0 (nt=1 is +16)
    const bf16x8* wmt0 = sm.w;
    const bf16x8* wmt1 = sm.w + KI * 64;

    // ---- pipelined stages: stage s runs L1(t=s) and L2(t=s-1) ----
    for (int s = 0; s <= Tt; ++s) {
        bool active = isL2 ? (s >= 1) : (s < Tt);
        if (active) {
            const int t = isL2 ? (s - 1) : s;
            f32x4 acc00 = {0,0,0,0}, acc01 = {0,0,0,0}, acc10 = {0,0,0,0}, acc11 = {0,0,0,0};
            if (!isL2) {
                // x-part: K [0,256) from y (fp32 -> bf16 inline)
                const float* x0 = y + ((size_t)nb0 * Tt + t) * Ff + quad * 8;
                const float* x1 = x0 + (size_t)16 * Tt * Ff;
                #pragma unroll
                for (int ki = 0; ki < 8; ++ki) {
                    bf16x8 a0 = wmt0[ki * 64 + lane];
                    bf16x8 a1 = wmt1[ki * 64 + lane];
                    bf16x8 b0, b1;
                    #pragma unroll
                    for (int e = 0; e < 8; ++e) {
                        b0[e] = (bf16)x0[ki * 32 + e];
                        b1[e] = (bf16)x1[ki * 32 + e];
                    }
                    acc00 = MFMA(a0, b0, acc00); acc10 = MFMA(a1, b0, acc10);
                    acc01 = MFMA(a0, b1, acc01); acc11 = MFMA(a1, b1, acc11);
                }
                if (t > 0) {    // h-part: K [256,1280) from h1[t-1]
                    const bf16* h1p = ((t - 1) & 1) ? h1b1 : h1b0;
                    const bf16* p0 = h1p + (size_t)nb0 * Hh + quad * 8;
                    const bf16* p1 = p0 + 16 * Hh;
                    #pragma unroll 4
                    for (int ki = 0; ki < 32; ++ki) {
                        bf16x8 a0 = wmt0[(8 + ki) * 64 + lane];
                        bf16x8 a1 = wmt1[(8 + ki) * 64 + lane];
                        bf16x8 b0 = *(const bf16x8*)(p0 + ki * 32);
                        bf16x8 b1 = *(const bf16x8*)(p1 + ki * 32);
                        acc00 = MFMA(a0, b0, acc00); acc10 = MFMA(a1, b0, acc10);
                        acc01 = MFMA(a0, b1, acc01); acc11 = MFMA(a1, b1, acc11);
                    }
                }
                bf16* hdst = (t & 1) ? h1b1 : h1b0;
                epilogue(sm, acc00, acc01, acc10, acc11, creg, hdst, hu0, false);
            } else {
                // h1-part: K [0,1024) from h1[t] (produced this pipeline by L1 blocks)
                const bf16* h1c = (t & 1) ? h1b1 : h1b0;
                const bf16* p0 = h1c + (size_t)nb0 * Hh + quad * 8;
                const bf16* p1 = p0 + 16 * Hh;
                #pragma unroll 4
                for (int ki = 0; ki < 32; ++ki) {
                    bf16x8 a0 = wmt0[ki * 64 + lane];
                    bf16x8 a1 = wmt1[ki * 64 + lane];
                    bf16x8 b0 = *(const bf16x8*)(p0 + ki * 32);
                    bf16x8 b1 = *(const bf16x8*)(p1 + ki * 32);
                    acc00 = MFMA(a0, b0, acc00); acc10 = MFMA(a1, b0, acc10);
                    acc01 = MFMA(a0, b1, acc01); acc11 = MFMA(a1, b1, acc11);
                }
                if (t > 0) {    // h2-part: K [1024,2048) from h2[t-1]
                    const bf16* h2p = ((t - 1) & 1) ? h2b1 : h2b0;
                    const bf16* q0 = h2p + (size_t)nb0 * Hh + quad * 8;
                    const bf16* q1 = q0 + 16 * Hh;
                    #pragma unroll 4
                    for (int ki = 0; ki < 32; ++ki) {
                        bf16x8 a0 = wmt0[(32 + ki) * 64 + lane];
                        bf16x8 a1 = wmt1[(32 + ki) * 64 + lane];
                        bf16x8 b0 = *(const bf16x8*)(q0 + ki * 32);
                        bf16x8 b1 = *(const bf16x8*)(q1 + ki * 32);
                        acc00 = MFMA(a0, b0, acc00); acc10 = MFMA(a1, b0, acc10);
                        acc01 = MFMA(a0, b1, acc01); acc11 = MFMA(a1, b1, acc11);
                    }
                }
                bf16* hdst = (t & 1) ? h2b1 : h2b0;
                epilogue(sm, acc00, acc01, acc10, acc11, creg, hdst, hu0, true);
            }
        }
        grid_barrier(cnt, (unsigned)(s + 1) * NBLK);
    }

    // ---- final: out = relu(h2[511] @ Wout^T + bout), h2[511] lives in h2b1 ----
    if (bid < 16) {
        const int bb = bid * 16 + l15;                       // batch
        const float* ap = Wout + (size_t)(wv * 16 + l15) * Hh + quad * 8;
        const bf16* bp = h2b1 + (size_t)bb * Hh + quad * 8;
        f32x4 acc = {0,0,0,0};
        #pragma unroll 4
        for (int ki = 0; ki < 32; ++ki) {
            bf16x8 a;
            #pragma unroll
            for (int e = 0; e < 8; ++e) a[e] = (bf16)ap[ki * 32 + e];
            bf16x8 b = *(const bf16x8*)(bp + ki * 32);
            acc = MFMA(a, b, acc);
        }
        #pragma unroll
        for (int r = 0; r < 4; ++r) {
            int orow = wv * 16 + quad * 4 + r;
            float v = acc[r] + bout[orow];
            out[(size_t)bb * Cc + orow] = fmaxf(v, 0.f);
        }
    }
}

extern "C" void kernel_launch(void* const* d_in, const int* in_sizes, int n_in,
                              void* d_out, int out_size, void* d_ws, size_t ws_size,
                              hipStream_t stream) {
    const float* y    = (const float*)d_in[0];
    const float* Wih1 = (const float*)d_in[1];
    const float* Whh1 = (const float*)d_in[2];
    const float* bih1 = (const float*)d_in[3];
    const float* bhh1 = (const float*)d_in[4];
    const float* Wih2 = (const float*)d_in[5];
    const float* Whh2 = (const float*)d_in[6];
    const float* bih2 = (const float*)d_in[7];
    const float* bhh2 = (const float*)d_in[8];
    const float* Wout = (const float*)d_in[9];
    const float* bout = (const float*)d_in[10];
    float* out = (float*)d_out;

    char* ws = (char*)d_ws;
    unsigned* cnt = (unsigned*)ws;                 // barrier counter (must start at 0)
    bf16* h1b0 = (bf16*)(ws + 4096);
    bf16* h1b1 = (bf16*)(ws + 4096 + 1 * 524288);
    bf16* h2b0 = (bf16*)(ws + 4096 + 2 * 524288);
    bf16* h2b1 = (bf16*)(ws + 4096 + 3 * 524288);

    hipMemsetAsync(ws, 0, 4096, stream);

    void* args[] = { &y, &Wih1, &Whh1, &bih1, &bhh1, &Wih2, &Whh2, &bih2, &bhh2,
                     &Wout, &bout, &out, &h1b0, &h1b1, &h2b0, &h2b1, &cnt };
    hipLaunchCooperativeKernel((void*)lstm_kernel, dim3(NBLK), dim3(NTHR), args, 0, stream);
}

// Round 2
// 19667.146 us; speedup vs baseline: 2.2766x; 2.2766x over previous
//
#include <hip/hip_runtime.h>
#include <hip/hip_bf16.h>

#define Bb 256
#define Tt 512
#define Ff 256
#define Hh 1024
#define Cc 128
#define NBLK 256
#define NTHR 512

typedef __bf16 bf16;
typedef bf16 bf16x8 __attribute__((ext_vector_type(8)));
typedef float f32x4 __attribute__((ext_vector_type(4)));

#define MFMA(a, b, c) __builtin_amdgcn_mfma_f32_16x16x32_bf16(a, b, c, 0, 0, 0)

struct SMem {
    bf16x8 w[2 * 64 * 64];      // MFMA A-frag order [(mt*KI+ki)*64+lane]; L2 blocks use all 128 KB
    float scratch[32 * 129];    // gate scratch, padded stride 129
    float bias[32];
    bf16 hstage[8 * 256];       // [hu][b] staging for coalesced h writeback
};

__device__ __forceinline__ float fsig(float x) {
    x = fminf(30.f, fmaxf(-30.f, x));
    return __builtin_amdgcn_rcpf(1.f + __expf(-x));
}
__device__ __forceinline__ float ftanh(float x) {
    x = fminf(15.f, fmaxf(-15.f, x));
    float e = __expf(2.f * x);
    return (e - 1.f) * __builtin_amdgcn_rcpf(e + 1.f);
}

// ---- device-scope (sc1) load/store: bypass non-coherent L1/L2, hit MALL ----
#define LDX4(dst, base, OFF) \
    asm volatile("global_load_dwordx4 %0, %1, off offset:" #OFF " sc1" : "=v"(dst) : "v"(base))

#define STX4(p, v) \
    asm volatile("global_store_dwordx4 %0, %1, off sc1" :: "v"(p), "v"(v) : "memory")

// issue 16 coherent loads (one 8-iter chunk: 8 from P0, 8 from P1)
#define ISSUE_CHUNK(B0, B1, P0, P1) do { \
    LDX4(B0[0], (P0), 0);   LDX4(B0[1], (P0), 64);  LDX4(B0[2], (P0), 128); LDX4(B0[3], (P0), 192); \
    LDX4(B0[4], (P0), 256); LDX4(B0[5], (P0), 320); LDX4(B0[6], (P0), 384); LDX4(B0[7], (P0), 448); \
    LDX4(B1[0], (P1), 0);   LDX4(B1[1], (P1), 64);  LDX4(B1[2], (P1), 128); LDX4(B1[3], (P1), 192); \
    LDX4(B1[4], (P1), 256); LDX4(B1[5], (P1), 320); LDX4(B1[6], (P1), 384); LDX4(B1[7], (P1), 448); \
} while (0)

// wait until <= N vmem ops outstanding; tie the chunk's regs so MFMA can't be hoisted above
#define WAITV(N, B0, B1) \
    asm volatile("s_waitcnt vmcnt(" #N ")" : \
        "+v"(B0[0]), "+v"(B0[1]), "+v"(B0[2]), "+v"(B0[3]), \
        "+v"(B0[4]), "+v"(B0[5]), "+v"(B0[6]), "+v"(B0[7]), \
        "+v"(B1[0]), "+v"(B1[1]), "+v"(B1[2]), "+v"(B1[3]), \
        "+v"(B1[4]), "+v"(B1[5]), "+v"(B1[6]), "+v"(B1[7]) :: "memory")

#define MFMA8(ABASE, B0, B1) do { \
    _Pragma("unroll") \
    for (int _i = 0; _i < 8; ++_i) { \
        bf16x8 _a0 = wA0[((ABASE) + _i) * 64 + lane]; \
        bf16x8 _a1 = wA1[((ABASE) + _i) * 64 + lane]; \
        bf16x8 _b0 = __builtin_bit_cast(bf16x8, B0[_i]); \
        bf16x8 _b1 = __builtin_bit_cast(bf16x8, B1[_i]); \
        acc00 = MFMA(_a0, _b0, acc00); acc10 = MFMA(_a1, _b0, acc10); \
        acc01 = MFMA(_a0, _b1, acc01); acc11 = MFMA(_a1, _b1, acc11); \
    } \
} while (0)

// 32 k-iters (K=1024) against two batch-row groups, 2-chunk-deep coherent-load pipeline
__device__ __forceinline__ void mm32(const bf16x8* __restrict__ wA0, const bf16x8* __restrict__ wA1,
                                     int abase, const bf16* p0, const bf16* p1, int lane,
                                     f32x4& acc00, f32x4& acc01, f32x4& acc10, f32x4& acc11)
{
    f32x4 bx0[8], bx1[8], by0[8], by1[8];
    asm volatile("s_waitcnt vmcnt(0)" ::: "memory");   // exact-count precondition
    ISSUE_CHUNK(bx0, bx1, p0, p1);
    ISSUE_CHUNK(by0, by1, p0 + 256, p1 + 256);
    WAITV(16, bx0, bx1);
    MFMA8(abase + 0, bx0, bx1);
    ISSUE_CHUNK(bx0, bx1, p0 + 512, p1 + 512);
    WAITV(16, by0, by1);
    MFMA8(abase + 8, by0, by1);
    ISSUE_CHUNK(by0, by1, p0 + 768, p1 + 768);
    WAITV(16, bx0, bx1);
    MFMA8(abase + 16, bx0, bx1);
    WAITV(0, by0, by1);
    MFMA8(abase + 24, by0, by1);
}

// distributed-flag grid barrier: no RMW, no cache-wide fences
__device__ __forceinline__ void grid_barrier2(unsigned* arrive, unsigned target, int tid, int bid) {
    __syncthreads();   // compiler emits s_waitcnt vmcnt(0) before s_barrier -> sc1 h-stores are device-visible
    if (tid == 0)
        __hip_atomic_store(&arrive[bid], target, __ATOMIC_RELAXED, __HIP_MEMORY_SCOPE_AGENT);
    if (tid < 64) {
        for (;;) {
            int ok = 1;
            #pragma unroll
            for (int j = 0; j < 4; ++j) {
                unsigned v = __hip_atomic_load(&arrive[tid * 4 + j], __ATOMIC_RELAXED,
                                               __HIP_MEMORY_SCOPE_AGENT);
                ok &= (v >= target);
            }
            if (__all(ok)) break;
            __builtin_amdgcn_s_sleep(2);
        }
    }
    __syncthreads();
}

__device__ __forceinline__ void epilogue(SMem& sm, f32x4 acc00, f32x4 acc01, f32x4 acc10, f32x4 acc11,
                                         float creg[4], bf16* hdst, int hu0, bool extra_tanh) {
    const int tid = threadIdx.x;
    const int lane = tid & 63, wv = tid >> 6, quad = lane >> 4, l15 = lane & 15;
    const int colb = (wv & 3) * 32;
    #pragma unroll
    for (int ph = 0; ph < 2; ++ph) {
        if ((wv >> 2) == ph) {
            #pragma unroll
            for (int r = 0; r < 4; ++r) {
                sm.scratch[(quad * 4 + r) * 129 + colb + l15]           = acc00[r];
                sm.scratch[(quad * 4 + r) * 129 + colb + 16 + l15]      = acc01[r];
                sm.scratch[(16 + quad * 4 + r) * 129 + colb + l15]      = acc10[r];
                sm.scratch[(16 + quad * 4 + r) * 129 + colb + 16 + l15] = acc11[r];
            }
        }
        __syncthreads();
        #pragma unroll
        for (int pi = 0; pi < 2; ++pi) {
            int idx = pi * NTHR + tid;      // 0..1023
            int bl = idx & 127, hu = idx >> 7;
            float gi = sm.scratch[hu * 129 + bl]        + sm.bias[hu];
            float gf = sm.scratch[(8 + hu) * 129 + bl]  + sm.bias[8 + hu];
            float gg = sm.scratch[(16 + hu) * 129 + bl] + sm.bias[16 + hu];
            float go = sm.scratch[(24 + hu) * 129 + bl] + sm.bias[24 + hu];
            float iv = fsig(gi), fv = fsig(gf), gv = ftanh(gg), ov = fsig(go);
            float c = fv * creg[ph * 2 + pi] + iv * gv;
            creg[ph * 2 + pi] = c;
            float h = ov * ftanh(c);
            if (extra_tanh) h = ftanh(h);   // layer-2 recurrent state is tanh'd
            sm.hstage[hu * 256 + (bl + 128 * ph)] = (bf16)h;
        }
        __syncthreads();
    }
    if (tid < 256) {
        bf16x8 v;
        #pragma unroll
        for (int e = 0; e < 8; ++e) v[e] = sm.hstage[e * 256 + tid];
        bf16* p = hdst + (size_t)tid * Hh + hu0;
        f32x4 pv = __builtin_bit_cast(f32x4, v);
        STX4(p, pv);                        // device-visible write-through (sc1)
    }
}

__global__ void __launch_bounds__(NTHR, 2)
lstm_kernel(const float* __restrict__ y,
            const float* __restrict__ Wih1, const float* __restrict__ Whh1,
            const float* __restrict__ bih1, const float* __restrict__ bhh1,
            const float* __restrict__ Wih2, const float* __restrict__ Whh2,
            const float* __restrict__ bih2, const float* __restrict__ bhh2,
            const float* __restrict__ Wout, const float* __restrict__ bout,
            float* __restrict__ out,
            bf16* __restrict__ h1b0, bf16* __restrict__ h1b1,
            bf16* __restrict__ h2b0, bf16* __restrict__ h2b1,
            unsigned* __restrict__ arrive)
{
    __shared__ SMem sm;
    const int tid = threadIdx.x;
    const int bid = blockIdx.x;
    const bool isL2 = bid >= 128;
    const int hu0 = (bid & 127) * 8;
    const int KI = isL2 ? 64 : 40;      // k-iters: L1 K=1280 (8 x + 32 h), L2 K=2048
    const int lane = tid & 63;
    const int wv = tid >> 6;
    const int quad = lane >> 4;
    const int l15 = lane & 15;

    // ---- one-time init: bias + pack weights into LDS in MFMA A-frag order ----
    if (tid < 32) {
        int gate = tid >> 3, j = tid & 7;
        int grow = gate * Hh + hu0 + j;
        sm.bias[tid] = isL2 ? (bih2[grow] + bhh2[grow]) : (bih1[grow] + bhh1[grow]);
    }
    for (int slot = tid; slot < 2 * KI * 64; slot += NTHR) {
        int mt = slot / (KI * 64);
        int ki = (slot / 64) % KI;
        int ln = slot & 63;
        int row = mt * 16 + (ln & 15);
        int k = ki * 32 + (ln >> 4) * 8;
        int gate = row >> 3, j = row & 7;
        int grow = gate * Hh + hu0 + j;
        const float* src;
        if (!isL2) src = (k < Ff) ? (Wih1 + (size_t)grow * Ff + k) : (Whh1 + (size_t)grow * Hh + (k - Ff));
        else       src = (k < Hh) ? (Wih2 + (size_t)grow * Hh + k) : (Whh2 + (size_t)grow * Hh + (k - Hh));
        bf16x8 fr;
        #pragma unroll
        for (int e = 0; e < 8; ++e) fr[e] = (bf16)src[e];
        sm.w[slot] = fr;
    }
    float creg[4] = {0.f, 0.f, 0.f, 0.f};
    __syncthreads();

    const int nb0 = wv * 32 + l15;      // batch row for nt=0 (nt=1 is +16)
    const bf16x8* wA0 = sm.w;
    const bf16x8* wA1 = sm.w + KI * 64;

    // ---- pipelined stages: stage s runs L1(t=s) and L2(t=s-1) ----
    for (int s = 0; s <= Tt; ++s) {
        bool active = isL2 ? (s >= 1) : (s < Tt);
        if (active) {
            const int t = isL2 ? (s - 1) : s;
            f32x4 acc00 = {0,0,0,0}, acc01 = {0,0,0,0}, acc10 = {0,0,0,0}, acc11 = {0,0,0,0};
            if (!isL2) {
                // x-part: K [0,256) from y (fp32 -> bf16 inline; plain loads, y is launch-constant)
                const f32x4* x0v = (const f32x4*)(y + ((size_t)nb0 * Tt + t) * Ff) + quad * 2;
                const f32x4* x1v = x0v + (size_t)16 * Tt * (Ff / 4);
                #pragma unroll
                for (int ki = 0; ki < 8; ++ki) {
                    bf16x8 a0 = wA0[ki * 64 + lane];
                    bf16x8 a1 = wA1[ki * 64 + lane];
                    f32x4 u0 = x0v[ki * 8], u1 = x0v[ki * 8 + 1];
                    f32x4 w0 = x1v[ki * 8], w1 = x1v[ki * 8 + 1];
                    bf16x8 b0, b1;
                    #pragma unroll
                    for (int e = 0; e < 4; ++e) {
                        b0[e] = (bf16)u0[e]; b0[4 + e] = (bf16)u1[e];
                        b1[e] = (bf16)w0[e]; b1[4 + e] = (bf16)w1[e];
                    }
                    acc00 = MFMA(a0, b0, acc00); acc10 = MFMA(a1, b0, acc10);
                    acc01 = MFMA(a0, b1, acc01); acc11 = MFMA(a1, b1, acc11);
                }
                if (t > 0) {    // h-part: K [256,1280) from h1[t-1]
                    const bf16* h1p = ((t - 1) & 1) ? h1b1 : h1b0;
                    const bf16* p0 = h1p + (size_t)nb0 * Hh + quad * 8;
                    mm32(wA0, wA1, 8, p0, p0 + 16 * Hh, lane, acc00, acc01, acc10, acc11);
                }
                epilogue(sm, acc00, acc01, acc10, acc11, creg, (t & 1) ? h1b1 : h1b0, hu0, false);
            } else {
                // h1-part: K [0,1024) from h1[t] (produced this stage by L1 blocks)
                const bf16* h1c = (t & 1) ? h1b1 : h1b0;
                const bf16* p0 = h1c + (size_t)nb0 * Hh + quad * 8;
                mm32(wA0, wA1, 0, p0, p0 + 16 * Hh, lane, acc00, acc01, acc10, acc11);
                if (t > 0) {    // h2-part: K [1024,2048) from h2[t-1]
                    const bf16* h2p = ((t - 1) & 1) ? h2b1 : h2b0;
                    const bf16* q0 = h2p + (size_t)nb0 * Hh + quad * 8;
                    mm32(wA0, wA1, 32, q0, q0 + 16 * Hh, lane, acc00, acc01, acc10, acc11);
                }
                epilogue(sm, acc00, acc01, acc10, acc11, creg, (t & 1) ? h2b1 : h2b0, hu0, true);
            }
        }
        grid_barrier2(arrive, (unsigned)(s + 1), tid, bid);
    }

    // ---- final: out = relu(h2[511] @ Wout^T + bout); h2[511] is in h2b1.
    // Plain loads are safe here: all in-kernel h reads were sc1 (never filled L2),
    // and local-L2 copies from co-XCD writers were updated by their own stores.
    if (bid < 16) {
        const int bb = bid * 16 + l15;
        const float* ap = Wout + (size_t)(wv * 16 + l15) * Hh + quad * 8;
        const bf16* bp = h2b1 + (size_t)bb * Hh + quad * 8;
        f32x4 acc = {0,0,0,0};
        #pragma unroll 4
        for (int ki = 0; ki < 32; ++ki) {
            bf16x8 a;
            #pragma unroll
            for (int e = 0; e < 8; ++e) a[e] = (bf16)ap[ki * 32 + e];
            bf16x8 b = *(const bf16x8*)(bp + ki * 32);
            acc = MFMA(a, b, acc);
        }
        #pragma unroll
        for (int r = 0; r < 4; ++r) {
            int orow = wv * 16 + quad * 4 + r;
            float v = acc[r] + bout[orow];
            out[(size_t)bb * Cc + orow] = fmaxf(v, 0.f);
        }
    }
}

extern "C" void kernel_launch(void* const* d_in, const int* in_sizes, int n_in,
                              void* d_out, int out_size, void* d_ws, size_t ws_size,
                              hipStream_t stream) {
    const float* y    = (const float*)d_in[0];
    const float* Wih1 = (const float*)d_in[1];
    const float* Whh1 = (const float*)d_in[2];
    const float* bih1 = (const float*)d_in[3];
    const float* bhh1 = (const float*)d_in[4];
    const float* Wih2 = (const float*)d_in[5];
    const float* Whh2 = (const float*)d_in[6];
    const float* bih2 = (const float*)d_in[7];
    const float* bhh2 = (const float*)d_in[8];
    const float* Wout = (const float*)d_in[9];
    const float* bout = (const float*)d_in[10];
    float* out = (float*)d_out;

    char* ws = (char*)d_ws;
    unsigned* arrive = (unsigned*)ws;              // 256 dword flags (must start 0)
    bf16* h1b0 = (bf16*)(ws + 4096);
    bf16* h1b1 = (bf16*)(ws + 4096 + 1 * 524288);
    bf16* h2b0 = (bf16*)(ws + 4096 + 2 * 524288);
    bf16* h2b1 = (bf16*)(ws + 4096 + 3 * 524288);

    hipMemsetAsync(ws, 0, 4096, stream);

    void* args[] = { &y, &Wih1, &Whh1, &bih1, &bhh1, &Wih2, &Whh2, &bih2, &bhh2,
                     &Wout, &bout, &out, &h1b0, &h1b1, &h2b0, &h2b1, &arrive };
    hipLaunchCooperativeKernel((void*)lstm_kernel, dim3(NBLK), dim3(NTHR), args, 0, stream);
}